// Round 9
// baseline (300.840 us; speedup 1.0000x reference)
//
#include <hip/hip_runtime.h>

#define BB 16
#define NN 8
#define CC 3
#define HH 256
#define WW 256
#define PLANE (HH * WW)          // 65536
#define SLICE (CC * PLANE)       // 196608 elems per (b,n)
#define BN_TOT (BB * NN)         // 128

// padded packed image: zero guard ring so OOB taps load 0 (no masks needed)
#define PW 260
#define PH 258
#define PIMG (PH * PW)           // 67080 pixels, 8B each

// ws layout (packed path):
//   [0, 512):           flags[128]
//   [1024, 17408):      cnt[128], PADDED: one int per 128B line (stride 32 ints)
//   [20480, 24576):     inv[128][8] floats (ia,ib,ic,id,tx,ty,0,0)
//   [32768, +8.6MB):    packed [B][PH][PW] uint2/pixel
#define WS_FLAGS 0
#define WS_CNT   1024
#define CNT_STRIDE 32            // ints; 128B per counter line
#define WS_INV   20480
#define WS_PACK  32768
#define WS_NEED  (WS_PACK + (size_t)BB * PIMG * 8)

typedef unsigned int u32;
typedef u32 __attribute__((ext_vector_type(4))) u32x4;
typedef u32x4 __attribute__((aligned(8))) u32x4_a8;   // 8B-aligned 16B load

__device__ __forceinline__ u32 f2bf(float f) {        // RNE f32 -> bf16
    u32 u = __float_as_uint(f);
    return (u + 0x7fffu + ((u >> 16) & 1u)) >> 16;
}
__device__ __forceinline__ float bflo(u32 d) { return __uint_as_float(d << 16); }
__device__ __forceinline__ float bfhi(u32 d) { return __uint_as_float(d & 0xffff0000u); }

// ---------------- packed path ----------------

// 16 images * 258 padded rows = 4128 blocks, XCD-affine (image b on XCD b&7).
// Block slot==0 also computes inverse matrices (t<128) and zeroes flags+cnt
// (t>=128) -> replay-deterministic (repack precedes warp in every call).
__global__ __launch_bounds__(256) void repack_kernel(
    const float* __restrict__ img,     // [B][C][H][W]
    const float* __restrict__ tf,      // [B][N][6]
    uint2* __restrict__ packed,        // [B][PH][PW]
    float* __restrict__ inv,           // [128][8]
    int* __restrict__ flags,
    int* __restrict__ cnt)             // padded, stride CNT_STRIDE
{
    int slot = blockIdx.x;
    int xcd  = slot & 7;
    int j    = slot >> 3;                 // 0..515 (2 images x 258 rows)
    int hi   = (j >= PH) ? 1 : 0;
    int b    = xcd + (hi << 3);
    int r    = j - (hi ? PH : 0);         // padded row 0..257
    int t    = threadIdx.x;

    uint2* prow = packed + (size_t)b * PIMG + (size_t)r * PW;
    uint2 z; z.x = 0u; z.y = 0u;

    if (r == 0 || r == PH - 1) {
        prow[t] = z;
        if (t < 4) prow[256 + t] = z;
    } else {
        const float* p0 = img + (size_t)b * SLICE + (size_t)(r - 1) * WW + t;
        u32 h0 = f2bf(p0[0]);
        u32 h1 = f2bf(p0[PLANE]);
        u32 h2 = f2bf(p0[2 * PLANE]);
        uint2 d;
        d.x = h0 | (h1 << 16);
        d.y = h2;
        prow[t + 2] = d;
        if (t < 2)      prow[t] = z;          // cols 0,1
        else if (t < 4) prow[256 + t] = z;    // cols 258,259
    }

    if (slot == 0) {                          // r==0 pad-row block: spare ALU
        if (t < BN_TOT) {
            const float* M = tf + t * 6;
            float a  = M[0], bm = M[1], tx = M[2];
            float c  = M[3], dd = M[4], ty = M[5];
            float det = a * dd - bm * c;
            float* I = inv + t * 8;
            I[0] =  dd / det;  I[1] = -bm / det;
            I[2] = -c / det;   I[3] =  a / det;
            I[4] = tx;         I[5] = ty;
        } else {
            flags[t - BN_TOT] = 0;
            cnt[(t - BN_TOT) * CNT_STRIDE] = 0;
        }
    }
}

// 8192 blocks = 16 b * 8 n * 64 row-groups, XCD-affine by image (R7 geometry,
// measured best). Thread owns one x (lane-consecutive -> coalesced gathers)
// and 4 rows. One 16B gather per y-tap fetches both x-taps x 3 ch (bf16);
// guard band makes OOB taps load 0. Offsets computed first, all 8 gathers
// issued, then weight math runs under load latency. Fixup (-1 for all-zero
// slices) is fused via a per-slice completion counter: last of 64 blocks
// checks the flag -- no separate fixup dispatch.
__global__ __launch_bounds__(256) void warp_packed_kernel(
    const uint2* __restrict__ pk,      // [B][PH][PW]
    const float* __restrict__ inv,     // [128][8]
    float* __restrict__ out,           // [B][N][C][H][W]
    int* __restrict__ flags,
    int* __restrict__ cnt)             // padded, stride CNT_STRIDE
{
    int slot = blockIdx.x;
    int xcd  = slot & 7;
    int j    = slot >> 3;
    int b    = xcd + ((j >> 9) << 3);
    int wi   = j & 511;
    int n    = wi >> 6;
    int blk  = wi & 63;
    int bn   = (b << 3) + n;

    int x  = threadIdx.x;
    int yb = blk << 2;

    const float* I = inv + bn * 8;       // wave-uniform -> scalar loads
    float ia = I[0], ib = I[1], ic = I[2], idm = I[3];
    float tx = I[4], ty = I[5];

    const uint2* pb = pk + (size_t)b * PIMG;
    float dx  = (float)x - tx;
    float sxb = ia * dx;
    float syb = ic * dx;

    // pass 1a: padded offsets + fractional parts only (int-heavy, short)
    int   ofT[4], ofB[4];
    float wx[4], wy[4];
#pragma unroll
    for (int p = 0; p < 4; ++p) {
        float dy = (float)(yb + p) - ty;
        float sx = sxb + ib * dy;
        float sy = syb + idm * dy;
        float x0f = floorf(sx);
        float y0f = floorf(sy);
        wx[p] = sx - x0f;
        wy[p] = sy - y0f;
        int x0 = (int)x0f;
        int y0 = (int)y0f;

        int pcol = min(max(x0, -2), 256) + 2;      // -> [0,258]; OOB cells are 0
        int prT  = min(max(y0, -1), 256) + 1;      // -> [0,257]; pad rows are 0
        int prB  = min(max(y0 + 1, -1), 256) + 1;

        ofT[p] = prT * PW + pcol;
        ofB[p] = prB * PW + pcol;
    }

    // pass 2: issue all 8 pair-gathers (16B each, 8B-aligned), batched.
    u32x4 vt[4], vb[4];
#pragma unroll
    for (int p = 0; p < 4; ++p) {
        vt[p] = *reinterpret_cast<const u32x4_a8*>(pb + ofT[p]);
        vb[p] = *reinterpret_cast<const u32x4_a8*>(pb + ofB[p]);
    }
    // Keep all 8 loads issued before any use (counted vmcnt waits, not
    // per-use drains). Weight math below then hides load latency.
    __builtin_amdgcn_sched_barrier(0);

    // pass 1b: weights (runs while loads are in flight)
    float w00[4], w01[4], w10[4], w11[4];
#pragma unroll
    for (int p = 0; p < 4; ++p) {
        float owx = 1.f - wx[p], owy = 1.f - wy[p];
        w00[p] = owx * owy;
        w01[p] = wx[p] * owy;
        w10[p] = owx * wy[p];
        w11[p] = wx[p] * wy[p];
    }

    // pass 3: decode bf16, combine, store (oldest loads first)
    bool nz = false;
    float* orow = out + (size_t)bn * SLICE + (size_t)yb * WW + x;
#pragma unroll
    for (int p = 0; p < 4; ++p) {
        u32 a0 = vt[p].x, a1 = vt[p].y;            // v00: c0|c1, c2
        u32 b0 = vt[p].z, b1 = vt[p].w;            // v01
        u32 c0 = vb[p].x, c1 = vb[p].y;            // v10
        u32 d0 = vb[p].z, d1 = vb[p].w;            // v11

        float o0 = bflo(a0) * w00[p] + bflo(b0) * w01[p]
                 + bflo(c0) * w10[p] + bflo(d0) * w11[p];
        float o1 = bfhi(a0) * w00[p] + bfhi(b0) * w01[p]
                 + bfhi(c0) * w10[p] + bfhi(d0) * w11[p];
        float o2 = bflo(a1) * w00[p] + bflo(b1) * w01[p]
                 + bflo(c1) * w10[p] + bflo(d1) * w11[p];
        nz |= (o0 != 0.f) | (o1 != 0.f) | (o2 != 0.f);
        __builtin_nontemporal_store(o0, orow + p * WW);
        __builtin_nontemporal_store(o1, orow + PLANE + p * WW);
        __builtin_nontemporal_store(o2, orow + 2 * PLANE + p * WW);
    }

    // nz reduce (LDS, plain flag store -- no RMW storm: R6 lesson), then
    // per-slice completion counter. cnt is line-padded: 64 staggered RMWs
    // per 128B line, 128 independent lines -> negligible serialization.
    __shared__ int s_nz;
    __shared__ int s_do;
    if (threadIdx.x == 0) { s_nz = 0; s_do = 0; }
    __syncthreads();
    if (nz) s_nz = 1;            // benign race: all writers store 1
    __syncthreads();
    if (threadIdx.x == 0) {
        if (s_nz) flags[bn] = 1;             // benign same-value race
        __threadfence();                     // release: flag + NT stores drained
        int old = atomicAdd(&cnt[bn * CNT_STRIDE], 1);
        if (old == 63) {                     // last block of this slice
            __threadfence();                 // acquire
            s_do = (flags[bn] == 0);
        }
    }
    __syncthreads();
    if (s_do) {                              // all-zero slice: write -1 (never
        float4 m1 = make_float4(-1.f, -1.f, -1.f, -1.f);  // triggers in practice)
        float4* o4 = reinterpret_cast<float4*>(out + (size_t)bn * SLICE);
        for (int i = threadIdx.x; i < SLICE / 4; i += 256) o4[i] = m1;
    }
}

// ---------------- fallback path (R3 kernel, known-good, f32 direct) ----------------

__global__ __launch_bounds__(256) void warp_kernel(
    const float* __restrict__ img,
    const float* __restrict__ tf,
    float* __restrict__ out,
    int* __restrict__ flags)
{
    int slot = blockIdx.x;
    int xcd  = slot & 7;
    int j    = slot >> 3;
    int b    = xcd + ((j >> 9) << 3);
    int wi   = j & 511;
    int n    = wi >> 6;
    int blk  = wi & 63;
    int bn   = (b << 3) + n;

    int x  = threadIdx.x;
    int yb = blk << 2;

    const float* M = tf + bn * 6;
    float a  = M[0], bm = M[1], tx = M[2];
    float c  = M[3], d  = M[4], ty = M[5];
    float det = a * d - bm * c;
    float ia  =  d / det;
    float ib  = -bm / det;
    float ic  = -c / det;
    float idm =  a / det;

    const float* imgb = img + (size_t)b * SLICE;
    float dx = (float)x - tx;
    float sxb = ia * dx;
    float syb = ic * dx;

    bool nz = false;
    float* orow = out + (size_t)bn * SLICE + (size_t)yb * WW + x;

#pragma unroll
    for (int p = 0; p < 4; ++p) {
        float dy = (float)(yb + p) - ty;
        float sx = sxb + ib * dy;
        float sy = syb + idm * dy;
        float x0f = floorf(sx);
        float y0f = floorf(sy);
        float wx = sx - x0f;
        float wy = sy - y0f;
        int x0 = (int)x0f;
        int y0 = (int)y0f;

        float mx0 = (x0 >= 0 && x0 < WW)         ? 1.f : 0.f;
        float mx1 = (x0 + 1 >= 0 && x0 + 1 < WW) ? 1.f : 0.f;
        float my0 = (y0 >= 0 && y0 < HH)         ? 1.f : 0.f;
        float my1 = (y0 + 1 >= 0 && y0 + 1 < HH) ? 1.f : 0.f;

        int xc0 = min(max(x0, 0), WW - 1);
        int xc1 = min(max(x0 + 1, 0), WW - 1);
        int yc0 = min(max(y0, 0), HH - 1);
        int yc1 = min(max(y0 + 1, 0), HH - 1);

        int i00 = yc0 * WW + xc0;
        int i01 = yc0 * WW + xc1;
        int i10 = yc1 * WW + xc0;
        int i11 = yc1 * WW + xc1;

        float w00 = (1.f - wx) * (1.f - wy) * (mx0 * my0);
        float w01 = wx * (1.f - wy)         * (mx1 * my0);
        float w10 = (1.f - wx) * wy         * (mx0 * my1);
        float w11 = wx * wy                 * (mx1 * my1);

        float v[CC][4];
#pragma unroll
        for (int ch = 0; ch < CC; ++ch) {
            const float* pc = imgb + ch * PLANE;
            v[ch][0] = pc[i00];
            v[ch][1] = pc[i01];
            v[ch][2] = pc[i10];
            v[ch][3] = pc[i11];
        }

#pragma unroll
        for (int ch = 0; ch < CC; ++ch) {
            float o = v[ch][0] * w00 + v[ch][1] * w01
                    + v[ch][2] * w10 + v[ch][3] * w11;
            nz |= (o != 0.f);
            __builtin_nontemporal_store(o, orow + (size_t)ch * PLANE + p * WW);
        }
    }

    __shared__ int s_nz;
    if (threadIdx.x == 0) s_nz = 0;
    __syncthreads();
    if (nz) s_nz = 1;
    __syncthreads();
    if (threadIdx.x == 0 && s_nz) flags[bn] = 1;
}

__global__ __launch_bounds__(256) void fixup_kernel(
    float* __restrict__ out, const int* __restrict__ flags)
{
    int bn = blockIdx.x;
    if (flags[bn] != 0) return;
    float4 m1 = make_float4(-1.f, -1.f, -1.f, -1.f);
    float4* o4 = reinterpret_cast<float4*>(out + (size_t)bn * SLICE);
    for (int i = threadIdx.x; i < SLICE / 4; i += 256) o4[i] = m1;
}

extern "C" void kernel_launch(void* const* d_in, const int* in_sizes, int n_in,
                              void* d_out, int out_size, void* d_ws, size_t ws_size,
                              hipStream_t stream) {
    (void)in_sizes; (void)n_in; (void)out_size;
    const float* img = (const float*)d_in[0];
    const float* tf  = (const float*)d_in[1];
    float* out = (float*)d_out;
    char* ws = (char*)d_ws;
    int* flags = (int*)(ws + WS_FLAGS);

    if (ws_size >= WS_NEED) {
        uint2* packed = (uint2*)(ws + WS_PACK);
        float* inv    = (float*)(ws + WS_INV);
        int*   cnt    = (int*)(ws + WS_CNT);
        repack_kernel<<<BB * PH, 256, 0, stream>>>(img, tf, packed, inv, flags, cnt);
        warp_packed_kernel<<<BB * NN * 64, 256, 0, stream>>>(packed, inv, out, flags, cnt);
    } else {
        hipMemsetAsync(flags, 0, BN_TOT * sizeof(int), stream);
        warp_kernel<<<BB * NN * 64, 256, 0, stream>>>(img, tf, out, flags);
        fixup_kernel<<<BN_TOT, 256, 0, stream>>>(out, flags);
    }
}

// Round 10
// 28.651 us; speedup vs baseline: 10.5002x; 10.5002x over previous
//
#include <hip/hip_runtime.h>

#define BB 16
#define NN 8
#define CC 3
#define HH 256
#define WW 256
#define PLANE (HH * WW)          // 65536
#define SLICE (CC * PLANE)       // 196608 elems per (b,n)
#define BN_TOT (BB * NN)         // 128

// padded packed image: zero guard ring so OOB taps load 0 (no masks needed)
// rows: 1 top + 256 + 1 bottom = 258 ; cols: 2 left + 256 + 2 right = 260
#define PW 260
#define PH 258
#define PIMG (PH * PW)           // 67080 pixels, 8B each

// ws layout (packed path):
//   [0, 512):       flags[128]
//   [512, 4608):    inv[128][8] floats (ia,ib,ic,id,tx,ty,0,0)
//   [16384, ...):   packed [B][PH][PW] uint2/pixel: x=bf16(c0)|bf16(c1)<<16, y=bf16(c2)
#define WS_FLAGS 0
#define WS_INV   512
#define WS_PACK  16384
#define WS_NEED  (WS_PACK + (size_t)BB * PIMG * 8)

typedef unsigned int u32;
typedef u32 __attribute__((ext_vector_type(4))) u32x4;
typedef u32x4 __attribute__((aligned(8))) u32x4_a8;   // 8B-aligned 16B load

__device__ __forceinline__ u32 f2bf(float f) {        // RNE f32 -> bf16
    u32 u = __float_as_uint(f);
    return (u + 0x7fffu + ((u >> 16) & 1u)) >> 16;
}
__device__ __forceinline__ float bflo(u32 d) { return __uint_as_float(d << 16); }
__device__ __forceinline__ float bfhi(u32 d) { return __uint_as_float(d & 0xffff0000u); }

// ---------------- packed path ----------------

// 16 images * 258 padded rows = 4128 blocks, XCD-affine (image b on XCD b&7).
__global__ __launch_bounds__(256) void repack_kernel(
    const float* __restrict__ img,     // [B][C][H][W]
    const float* __restrict__ tf,      // [B][N][6]
    uint2* __restrict__ packed,        // [B][PH][PW]
    float* __restrict__ inv,           // [128][8]
    int* __restrict__ flags)
{
    int slot = blockIdx.x;
    int xcd  = slot & 7;
    int j    = slot >> 3;                 // 0..515 (2 images x 258 rows)
    int hi   = (j >= PH) ? 1 : 0;
    int b    = xcd + (hi << 3);
    int r    = j - (hi ? PH : 0);         // padded row 0..257
    int t    = threadIdx.x;

    uint2* prow = packed + (size_t)b * PIMG + (size_t)r * PW;
    uint2 z; z.x = 0u; z.y = 0u;

    if (r == 0 || r == PH - 1) {
        prow[t] = z;
        if (t < 4) prow[256 + t] = z;
    } else {
        const float* p0 = img + (size_t)b * SLICE + (size_t)(r - 1) * WW + t;
        u32 h0 = f2bf(p0[0]);
        u32 h1 = f2bf(p0[PLANE]);
        u32 h2 = f2bf(p0[2 * PLANE]);
        uint2 d;
        d.x = h0 | (h1 << 16);
        d.y = h2;
        prow[t + 2] = d;
        if (t < 2)      prow[t] = z;          // cols 0,1
        else if (t < 4) prow[256 + t] = z;    // cols 258,259
    }

    if (slot == 0) {                          // r==0 pad-row block: spare ALU
        if (t < BN_TOT) {
            const float* M = tf + t * 6;
            float a  = M[0], bm = M[1], tx = M[2];
            float c  = M[3], dd = M[4], ty = M[5];
            float det = a * dd - bm * c;
            float* I = inv + t * 8;
            I[0] =  dd / det;  I[1] = -bm / det;
            I[2] = -c / det;   I[3] =  a / det;
            I[4] = tx;         I[5] = ty;
        } else {
            flags[t - BN_TOT] = 0;
        }
    }
}

// 8192 blocks = 16 b * 8 n * 64 row-groups, XCD-affine by image (measured-best
// R7 geometry). Thread owns one x (lane-consecutive -> coalesced gathers) and
// 4 rows. One 16B gather per y-tap fetches both x-taps x 3 ch (bf16); guard
// band makes OOB taps load 0 -> no validity masks, no edge selects.
__global__ __launch_bounds__(256) void warp_packed_kernel(
    const uint2* __restrict__ pk,      // [B][PH][PW]
    const float* __restrict__ inv,     // [128][8]
    float* __restrict__ out,           // [B][N][C][H][W]
    int* __restrict__ flags)
{
    int slot = blockIdx.x;
    int xcd  = slot & 7;
    int j    = slot >> 3;
    int b    = xcd + ((j >> 9) << 3);
    int wi   = j & 511;
    int n    = wi >> 6;
    int blk  = wi & 63;
    int bn   = (b << 3) + n;

    int x  = threadIdx.x;
    int yb = blk << 2;

    const float* I = inv + bn * 8;       // wave-uniform -> scalar loads
    float ia = I[0], ib = I[1], ic = I[2], idm = I[3];
    float tx = I[4], ty = I[5];

    const uint2* pb = pk + (size_t)b * PIMG;
    float dx  = (float)x - tx;
    float sxb = ia * dx;
    float syb = ic * dx;

    // pass 1: padded offsets + weights, all 4 rows (no masks)
    int   ofT[4], ofB[4];
    float w00[4], w01[4], w10[4], w11[4];
#pragma unroll
    for (int p = 0; p < 4; ++p) {
        float dy = (float)(yb + p) - ty;
        float sx = sxb + ib * dy;
        float sy = syb + idm * dy;
        float x0f = floorf(sx);
        float y0f = floorf(sy);
        float wx = sx - x0f;
        float wy = sy - y0f;
        int x0 = (int)x0f;
        int y0 = (int)y0f;

        int pcol = min(max(x0, -2), 256) + 2;      // -> [0,258]; OOB cells are 0
        int prT  = min(max(y0, -1), 256) + 1;      // -> [0,257]; pad rows are 0
        int prB  = min(max(y0 + 1, -1), 256) + 1;

        ofT[p] = prT * PW + pcol;
        ofB[p] = prB * PW + pcol;

        float owx = 1.f - wx, owy = 1.f - wy;
        w00[p] = owx * owy;
        w01[p] = wx * owy;
        w10[p] = owx * wy;
        w11[p] = wx * wy;
    }

    // pass 2: issue all 8 pair-gathers (16B each, 8B-aligned), batched.
    u32x4 vt[4], vb[4];
#pragma unroll
    for (int p = 0; p < 4; ++p) {
        vt[p] = *reinterpret_cast<const u32x4_a8*>(pb + ofT[p]);
        vb[p] = *reinterpret_cast<const u32x4_a8*>(pb + ofB[p]);
    }
    // Keep all 8 loads issued before any use (counted vmcnt waits, not
    // per-use drains). Without this the compiler sinks loads into pass 3.
    __builtin_amdgcn_sched_barrier(0);

    // pass 3: decode bf16, combine, store
    bool nz = false;
    float* orow = out + (size_t)bn * SLICE + (size_t)yb * WW + x;
#pragma unroll
    for (int p = 0; p < 4; ++p) {
        u32 a0 = vt[p].x, a1 = vt[p].y;            // v00: c0|c1, c2
        u32 b0 = vt[p].z, b1 = vt[p].w;            // v01
        u32 c0 = vb[p].x, c1 = vb[p].y;            // v10
        u32 d0 = vb[p].z, d1 = vb[p].w;            // v11

        float o0 = bflo(a0) * w00[p] + bflo(b0) * w01[p]
                 + bflo(c0) * w10[p] + bflo(d0) * w11[p];
        float o1 = bfhi(a0) * w00[p] + bfhi(b0) * w01[p]
                 + bfhi(c0) * w10[p] + bfhi(d0) * w11[p];
        float o2 = bflo(a1) * w00[p] + bflo(b1) * w01[p]
                 + bflo(c1) * w10[p] + bflo(d1) * w11[p];
        nz |= (o0 != 0.f) | (o1 != 0.f) | (o2 != 0.f);
        __builtin_nontemporal_store(o0, orow + p * WW);
        __builtin_nontemporal_store(o1, orow + PLANE + p * WW);
        __builtin_nontemporal_store(o2, orow + 2 * PLANE + p * WW);
    }

    // nz reduction: LDS reduce, then ONE plain store per block.
    // R6 lesson: no per-wave atomic RMWs (32K same-line RMWs cost ~95us).
    // R9 lesson: no __threadfence / fused fixup (device-scope fence per
    // block drains NT stores + L2 -> 300us). Separate tiny dispatch wins.
    __shared__ int s_nz;
    if (threadIdx.x == 0) s_nz = 0;
    __syncthreads();
    if (nz) s_nz = 1;            // benign race: all writers store 1
    __syncthreads();
    if (threadIdx.x == 0 && s_nz) flags[bn] = 1;   // benign same-value race
}

// ---------------- fallback path (R3 kernel, known-good, f32 direct) ----------------

__global__ __launch_bounds__(256) void warp_kernel(
    const float* __restrict__ img,
    const float* __restrict__ tf,
    float* __restrict__ out,
    int* __restrict__ flags)
{
    int slot = blockIdx.x;
    int xcd  = slot & 7;
    int j    = slot >> 3;
    int b    = xcd + ((j >> 9) << 3);
    int wi   = j & 511;
    int n    = wi >> 6;
    int blk  = wi & 63;
    int bn   = (b << 3) + n;

    int x  = threadIdx.x;
    int yb = blk << 2;

    const float* M = tf + bn * 6;
    float a  = M[0], bm = M[1], tx = M[2];
    float c  = M[3], d  = M[4], ty = M[5];
    float det = a * d - bm * c;
    float ia  =  d / det;
    float ib  = -bm / det;
    float ic  = -c / det;
    float idm =  a / det;

    const float* imgb = img + (size_t)b * SLICE;
    float dx = (float)x - tx;
    float sxb = ia * dx;
    float syb = ic * dx;

    bool nz = false;
    float* orow = out + (size_t)bn * SLICE + (size_t)yb * WW + x;

#pragma unroll
    for (int p = 0; p < 4; ++p) {
        float dy = (float)(yb + p) - ty;
        float sx = sxb + ib * dy;
        float sy = syb + idm * dy;
        float x0f = floorf(sx);
        float y0f = floorf(sy);
        float wx = sx - x0f;
        float wy = sy - y0f;
        int x0 = (int)x0f;
        int y0 = (int)y0f;

        float mx0 = (x0 >= 0 && x0 < WW)         ? 1.f : 0.f;
        float mx1 = (x0 + 1 >= 0 && x0 + 1 < WW) ? 1.f : 0.f;
        float my0 = (y0 >= 0 && y0 < HH)         ? 1.f : 0.f;
        float my1 = (y0 + 1 >= 0 && y0 + 1 < HH) ? 1.f : 0.f;

        int xc0 = min(max(x0, 0), WW - 1);
        int xc1 = min(max(x0 + 1, 0), WW - 1);
        int yc0 = min(max(y0, 0), HH - 1);
        int yc1 = min(max(y0 + 1, 0), HH - 1);

        int i00 = yc0 * WW + xc0;
        int i01 = yc0 * WW + xc1;
        int i10 = yc1 * WW + xc0;
        int i11 = yc1 * WW + xc1;

        float w00 = (1.f - wx) * (1.f - wy) * (mx0 * my0);
        float w01 = wx * (1.f - wy)         * (mx1 * my0);
        float w10 = (1.f - wx) * wy         * (mx0 * my1);
        float w11 = wx * wy                 * (mx1 * my1);

        float v[CC][4];
#pragma unroll
        for (int ch = 0; ch < CC; ++ch) {
            const float* pc = imgb + ch * PLANE;
            v[ch][0] = pc[i00];
            v[ch][1] = pc[i01];
            v[ch][2] = pc[i10];
            v[ch][3] = pc[i11];
        }

#pragma unroll
        for (int ch = 0; ch < CC; ++ch) {
            float o = v[ch][0] * w00 + v[ch][1] * w01
                    + v[ch][2] * w10 + v[ch][3] * w11;
            nz |= (o != 0.f);
            __builtin_nontemporal_store(o, orow + (size_t)ch * PLANE + p * WW);
        }
    }

    __shared__ int s_nz;
    if (threadIdx.x == 0) s_nz = 0;
    __syncthreads();
    if (nz) s_nz = 1;
    __syncthreads();
    if (threadIdx.x == 0 && s_nz) flags[bn] = 1;
}

__global__ __launch_bounds__(256) void fixup_kernel(
    float* __restrict__ out, const int* __restrict__ flags)
{
    int bn = blockIdx.x;
    if (flags[bn] != 0) return;
    float4 m1 = make_float4(-1.f, -1.f, -1.f, -1.f);
    float4* o4 = reinterpret_cast<float4*>(out + (size_t)bn * SLICE);
    for (int i = threadIdx.x; i < SLICE / 4; i += 256) o4[i] = m1;
}

extern "C" void kernel_launch(void* const* d_in, const int* in_sizes, int n_in,
                              void* d_out, int out_size, void* d_ws, size_t ws_size,
                              hipStream_t stream) {
    (void)in_sizes; (void)n_in; (void)out_size;
    const float* img = (const float*)d_in[0];
    const float* tf  = (const float*)d_in[1];
    float* out = (float*)d_out;
    char* ws = (char*)d_ws;
    int* flags = (int*)(ws + WS_FLAGS);

    if (ws_size >= WS_NEED) {
        uint2* packed = (uint2*)(ws + WS_PACK);
        float* inv    = (float*)(ws + WS_INV);
        repack_kernel<<<BB * PH, 256, 0, stream>>>(img, tf, packed, inv, flags);
        warp_packed_kernel<<<BB * NN * 64, 256, 0, stream>>>(packed, inv, out, flags);
    } else {
        hipMemsetAsync(flags, 0, BN_TOT * sizeof(int), stream);
        warp_kernel<<<BB * NN * 64, 256, 0, stream>>>(img, tf, out, flags);
    }
    fixup_kernel<<<BN_TOT, 256, 0, stream>>>(out, flags);
}